// Round 9
// baseline (314.447 us; speedup 1.0000x reference)
//
#include <hip/hip_runtime.h>

#define NN 50000
#define NE 800000
#define DD 128
#define NSTRIP 3125   // NN/16
#define NB 196        // dst>>8 buckets (49999>>8 == 195)
#define CHUNK 4096    // edges per shuf/hist block; grid = ceil(NE/CHUNK) = 196
#define MAXB 6144     // bucket capacity (mean 4082, sigma ~64 -> +32 sigma)
#define BPT 12500     // agg blocks per column tile (NN/4 waves-per-block)

// workspace layout, element (4-byte word) offsets
#define OF_BCNT  0            // int[256] bucket counts
#define OF_BBASE 256          // int[257] bucket bases
#define OF_BCUR  768          // int[256] bucket cursors
#define OF_DINV  1024         // float[NN]
#define OF_OFFS  51200        // int[NN+1]
#define OF_TMP   101632       // uint[NE] packed (src<<8 | dstlow)  (3.2 MB)
#define OF_CSRU  901632       // ushort[NE] sorted src  (1.6 MB)
#define OF_G     1301632      // ushort[4][NN][32] bf16 g, COLUMN-TILED (3.2MB/tile)
#define OF_X2    4501632      // float[NN*DD] layer-2 input
#define OF_W1H   10901632     // ushort[16384] fragment order
#define OF_W1L   10909824
#define OF_W2H   10918016
#define OF_W2L   10926208     // end 10934400 words = 43.7 MB

typedef __attribute__((ext_vector_type(8))) short bf8_t;   // 8 bf16 = 4 VGPRs
typedef __attribute__((ext_vector_type(4))) float f32x4;

static __device__ __forceinline__ unsigned short f2bf(float f) {
    unsigned int u = __float_as_uint(f);
    unsigned int r = (u + 0x7fffu + ((u >> 16) & 1u)) >> 16;   // RNE
    return (unsigned short)r;
}
static __device__ __forceinline__ float bf2f(unsigned short h) {
    return __uint_as_float(((unsigned int)h) << 16);
}

// both W conversions in one launch; block 0 also zeroes the bucket counters.
// frag g=(ntile*4+kk)*64+lane holds B[k=kk*32+(lane>>4)*8+j][n=ntile*16+(lane&15)]
__global__ void k_wconv(const float* __restrict__ W1, const float* __restrict__ W2,
                        ushort* __restrict__ w1h, ushort* __restrict__ w1l,
                        ushort* __restrict__ w2h, ushort* __restrict__ w2l,
                        int* __restrict__ bcnt) {
    if (blockIdx.x == 0) bcnt[threadIdx.x] = 0;
    int gg = blockIdx.x * 256 + threadIdx.x;
    const float* W = (gg < 2048) ? W1 : W2;
    ushort* wh = (gg < 2048) ? w1h : w2h;
    ushort* wl = (gg < 2048) ? w1l : w2l;
    int g = gg & 2047;
    int ntile = g >> 8;
    int kk = (g >> 6) & 3;
    int lane = g & 63;
    int k0 = kk * 32 + ((lane >> 4) * 8);
    int col = ntile * 16 + (lane & 15);
#pragma unroll
    for (int j = 0; j < 8; ++j) {
        float w = W[(k0 + j) * DD + col];
        unsigned short h = f2bf(w);
        wh[(size_t)g * 8 + j] = h;
        wl[(size_t)g * 8 + j] = f2bf(w - bf2f(h));
    }
}

// 256-bucket histogram of dst>>8, LDS-aggregated
__global__ void k_hist(const int* __restrict__ dst, int* __restrict__ bcnt) {
    __shared__ int lc[256];
    int tid = threadIdx.x;
    lc[tid] = 0;
    __syncthreads();
    int e0 = blockIdx.x * CHUNK;
    int e1 = e0 + CHUNK; if (e1 > NE) e1 = NE;
    for (int e = e0 + tid; e < e1; e += 256)
        atomicAdd(&lc[dst[e] >> 8], 1);
    __syncthreads();
    if (lc[tid]) atomicAdd(&bcnt[tid], lc[tid]);
}

// single-block scan of bucket counts -> bases + cursors; offs[NN] = NE
__global__ void k_bscan(const int* __restrict__ bcnt, int* __restrict__ bbase,
                        int* __restrict__ bcur, int* __restrict__ offs) {
    __shared__ int sh[256];
    int tid = threadIdx.x;
    int v = bcnt[tid];
    sh[tid] = v;
    __syncthreads();
    for (int o = 1; o < 256; o <<= 1) {
        int t = (tid >= o) ? sh[tid - o] : 0;
        __syncthreads();
        sh[tid] += t;
        __syncthreads();
    }
    bbase[tid] = sh[tid] - v;
    bcur[tid]  = sh[tid] - v;
    if (tid == 255) bbase[256] = sh[255];
    if (tid == 0) offs[NN] = NE;
}

// shuffle edges into coarse buckets.  Per block: LDS histogram of its chunk,
// ONE global atomic per touched bucket to reserve a contiguous run, then
// write packed entries -> per-block addresses form ~contiguous runs per
// bucket (lines mostly written by a single block -> no cross-XCD bouncing).
__global__ void k_shuf(const int* __restrict__ src, const int* __restrict__ dst,
                       int* __restrict__ bcur, unsigned int* __restrict__ tmp) {
    __shared__ int lcnt[256];
    __shared__ int lbase[256];
    __shared__ int lcur[256];
    int tid = threadIdx.x;
    lcnt[tid] = 0;
    __syncthreads();
    int e0 = blockIdx.x * CHUNK;
    int e1 = e0 + CHUNK; if (e1 > NE) e1 = NE;
    for (int e = e0 + tid; e < e1; e += 256)
        atomicAdd(&lcnt[dst[e] >> 8], 1);
    __syncthreads();
    if (lcnt[tid]) lbase[tid] = atomicAdd(&bcur[tid], lcnt[tid]);
    lcur[tid] = 0;
    __syncthreads();
    for (int e = e0 + tid; e < e1; e += 256) {
        int d = dst[e], s = src[e];
        int b = d >> 8;
        int r = atomicAdd(&lcur[b], 1);
        tmp[lbase[b] + r] = ((unsigned int)s << 8) | (unsigned int)(d & 255);
    }
}

// per-bucket LDS counting sort -> final CSR slab, offs[], dinv[].
__global__ __launch_bounds__(256) void k_sort(const int* __restrict__ bbase,
                                              const unsigned int* __restrict__ tmp,
                                              ushort* __restrict__ csru,
                                              int* __restrict__ offs,
                                              float* __restrict__ dinv) {
    __shared__ unsigned int ent[MAXB];
    __shared__ int cnt[256];
    __shared__ int boff[256];
    __shared__ int cur[256];
    int b = blockIdx.x, tid = threadIdx.x;
    int base = bbase[b];
    int nb = bbase[b + 1] - base;
    cnt[tid] = 0;
    __syncthreads();
    for (int i = tid; i < nb; i += 256) {
        unsigned int v = tmp[base + i];
        ent[i] = v;
        atomicAdd(&cnt[v & 255], 1);
    }
    __syncthreads();
    int v = cnt[tid];
    boff[tid] = v;
    __syncthreads();
    for (int o = 1; o < 256; o <<= 1) {
        int t = (tid >= o) ? boff[tid - o] : 0;
        __syncthreads();
        boff[tid] += t;
        __syncthreads();
    }
    int excl = boff[tid] - v;
    int node = b * 256 + tid;
    if (node < NN) {
        offs[node] = base + excl;
        dinv[node] = rsqrtf((float)(v + 1));   // +1 self-loop
    }
    cur[tid] = excl;
    __syncthreads();
    for (int i = tid; i < nb; i += 256) {
        unsigned int e = ent[i];
        int bin = e & 255;
        int r = atomicAdd(&cur[bin], 1);
        csru[base + r] = (ushort)(e >> 8);
    }
}

// MFMA GEMM, split-bf16 (hi*hi + hi*lo + lo*hi ~ fp32 accuracy).
// Reads fp32 X directly, Dekker-splits in-register.
// Epilogue scales rows by dinv, stores bf16 g COLUMN-TILED:
// g[tile][node][c] , tile = col>>5, c = col&31  (3.2MB per tile < 4MiB L2).
__global__ __launch_bounds__(256) void k_mgemm(const float* __restrict__ X,
                                               const ushort* __restrict__ wh,
                                               const ushort* __restrict__ wl,
                                               const float* __restrict__ dinv,
                                               ushort* __restrict__ G) {
    int wave = threadIdx.x >> 6;
    int lane = threadIdx.x & 63;
    int strip = blockIdx.x * 4 + wave;
    if (strip >= NSTRIP) return;
    int rb = strip << 4;
    int m = lane & 15;
    int quad = lane >> 4;
    const float* ar = X + (size_t)(rb + m) * DD;
    f32x4 acc[8];
#pragma unroll
    for (int t = 0; t < 8; ++t) acc[t] = (f32x4){0.f, 0.f, 0.f, 0.f};
#pragma unroll
    for (int kk = 0; kk < 4; ++kk) {
        float4 xa = *(const float4*)(ar + kk * 32 + quad * 8);
        float4 xb = *(const float4*)(ar + kk * 32 + quad * 8 + 4);
        float xs[8] = {xa.x, xa.y, xa.z, xa.w, xb.x, xb.y, xb.z, xb.w};
        bf8_t ah, al;
#pragma unroll
        for (int j = 0; j < 8; ++j) {
            unsigned short hh = f2bf(xs[j]);
            ah[j] = (short)hh;
            al[j] = (short)f2bf(xs[j] - bf2f(hh));
        }
#pragma unroll
        for (int t = 0; t < 8; ++t) {
            size_t bo = ((size_t)(t * 4 + kk) * 64 + lane) * 8;
            bf8_t bh = *(const bf8_t*)(wh + bo);
            bf8_t bl = *(const bf8_t*)(wl + bo);
            acc[t] = __builtin_amdgcn_mfma_f32_16x16x32_bf16(ah, bh, acc[t], 0, 0, 0);
            acc[t] = __builtin_amdgcn_mfma_f32_16x16x32_bf16(ah, bl, acc[t], 0, 0, 0);
            acc[t] = __builtin_amdgcn_mfma_f32_16x16x32_bf16(al, bh, acc[t], 0, 0, 0);
        }
    }
    // C/D layout (m89-verified): col = lane&15, row = quad*4 + reg
    float dv[4];
#pragma unroll
    for (int r = 0; r < 4; ++r) dv[r] = dinv[rb + quad * 4 + r];
#pragma unroll
    for (int t = 0; t < 8; ++t) {
        int tile = t >> 1;
        int cin  = (t & 1) * 16 + m;
#pragma unroll
        for (int r = 0; r < 4; ++r)
            G[((size_t)tile * NN + (rb + quad * 4 + r)) * 32 + cin] =
                f2bf(dv[r] * acc[t][r]);
    }
}

// out[i][tile cols] = relu( dinv[i]*(sum_{e:dst==i} g[t][src_e] + g[t][i]) + b )
// Column-tiled: one wave per (node, 32-col tile).  Each edge read = ONE 64B
// line from the 3.2MB L2-resident tile.  Lane = slot(q: edge)*16 + l(col
// pair); 2x unroll -> 2 lines in flight; cross-slot reduce via shfl_xor.
// Grid is tile-major so co-resident blocks share a tile in L2.
__global__ void k_agg(const ushort* __restrict__ g, const float* __restrict__ dinv,
                      const int* __restrict__ offs, const ushort* __restrict__ csru,
                      const float* __restrict__ bias, float* __restrict__ outf) {
    int wave = threadIdx.x >> 6;
    int lane = threadIdx.x & 63;
    int tile = blockIdx.x / BPT;
    int node = (blockIdx.x % BPT) * 4 + wave;   // BPT*4 == NN exactly
    int q = lane >> 4;
    int l = lane & 15;
    const ushort* gt = g + (size_t)tile * NN * 32;
    float2 a0 = {0.f, 0.f}, a1 = {0.f, 0.f};
    int e  = offs[node] + q;
    int e1 = offs[node + 1];
    for (; e + 4 < e1; e += 8) {
        int s0 = csru[e];
        int s1 = csru[e + 4];
        ushort2 v0 = *(const ushort2*)(gt + (size_t)s0 * 32 + 2 * l);
        ushort2 v1 = *(const ushort2*)(gt + (size_t)s1 * 32 + 2 * l);
        a0.x += bf2f(v0.x); a0.y += bf2f(v0.y);
        a1.x += bf2f(v1.x); a1.y += bf2f(v1.y);
    }
    if (e < e1) {
        int s0 = csru[e];
        ushort2 v0 = *(const ushort2*)(gt + (size_t)s0 * 32 + 2 * l);
        a0.x += bf2f(v0.x); a0.y += bf2f(v0.y);
    }
    if (q == 0) {  // self-loop term, counted once
        ushort2 v = *(const ushort2*)(gt + (size_t)node * 32 + 2 * l);
        a0.x += bf2f(v.x); a0.y += bf2f(v.y);
    }
    a0.x += a1.x; a0.y += a1.y;
    a0.x += __shfl_xor(a0.x, 16, 64);
    a0.y += __shfl_xor(a0.y, 16, 64);
    a0.x += __shfl_xor(a0.x, 32, 64);
    a0.y += __shfl_xor(a0.y, 32, 64);
    if (q == 0) {
        float di = dinv[node];
        float2 bv = *(const float2*)(bias + tile * 32 + 2 * l);
        float2 o;
        o.x = fmaxf(di * a0.x + bv.x, 0.f);
        o.y = fmaxf(di * a0.y + bv.y, 0.f);
        *(float2*)(outf + (size_t)node * DD + tile * 32 + 2 * l) = o;
    }
}

extern "C" void kernel_launch(void* const* d_in, const int* in_sizes, int n_in,
                              void* d_out, int out_size, void* d_ws, size_t ws_size,
                              hipStream_t stream) {
    const float* x  = (const float*)d_in[0];
    const int*   ei = (const int*)d_in[1];
    const float* W1 = (const float*)d_in[2];
    const float* b1 = (const float*)d_in[3];
    const float* W2 = (const float*)d_in[4];
    const float* b2 = (const float*)d_in[5];
    float* out = (float*)d_out;

    const int* src = ei;        // edge_index[0]
    const int* dst = ei + NE;   // edge_index[1]

    int*          wsi  = (int*)d_ws;
    float*        wsf  = (float*)d_ws;
    ushort*       wsu  = (ushort*)d_ws;
    unsigned int* wsuw = (unsigned int*)d_ws;
    int*    bcnt  = wsi + OF_BCNT;
    int*    bbase = wsi + OF_BBASE;
    int*    bcur  = wsi + OF_BCUR;
    float*  dinv  = wsf + OF_DINV;
    int*    offs  = wsi + OF_OFFS;
    unsigned int* tmp = wsuw + OF_TMP;
    ushort* csru  = wsu + (size_t)OF_CSRU * 2;
    ushort* gbuf  = wsu + (size_t)OF_G * 2;
    float*  x2    = wsf + OF_X2;
    ushort* w1h   = wsu + (size_t)OF_W1H * 2;
    ushort* w1l   = wsu + (size_t)OF_W1L * 2;
    ushort* w2h   = wsu + (size_t)OF_W2H * 2;
    ushort* w2l   = wsu + (size_t)OF_W2L * 2;

    const int chunks = (NE + CHUNK - 1) / CHUNK;  // 196

    // W conversions + bcnt zeroing (one launch), then bucket-sort CSR build
    hipLaunchKernelGGL(k_wconv, dim3(16), dim3(256), 0, stream,
                       W1, W2, w1h, w1l, w2h, w2l, bcnt);
    hipLaunchKernelGGL(k_hist,  dim3(chunks), dim3(256), 0, stream, dst, bcnt);
    hipLaunchKernelGGL(k_bscan, dim3(1), dim3(256), 0, stream, bcnt, bbase, bcur, offs);
    hipLaunchKernelGGL(k_shuf,  dim3(chunks), dim3(256), 0, stream, src, dst, bcur, tmp);
    hipLaunchKernelGGL(k_sort,  dim3(NB), dim3(256), 0, stream, bbase, tmp, csru, offs, dinv);

    const int gblocks = (NSTRIP + 3) / 4;  // 782

    // layer 1: g = dinv*(x @ W1) (MFMA, tiled bf16) ; agg -> relu(dinv*sum+b1)
    hipLaunchKernelGGL(k_mgemm, dim3(gblocks), dim3(256), 0, stream, x, w1h, w1l, dinv, gbuf);
    hipLaunchKernelGGL(k_agg,   dim3(4 * BPT), dim3(256), 0, stream,
                       gbuf, dinv, offs, csru, b1, x2);
    // layer 2
    hipLaunchKernelGGL(k_mgemm, dim3(gblocks), dim3(256), 0, stream, x2, w2h, w2l, dinv, gbuf);
    hipLaunchKernelGGL(k_agg,   dim3(4 * BPT), dim3(256), 0, stream,
                       gbuf, dinv, offs, csru, b2, out);
}

// Round 10
// 217.335 us; speedup vs baseline: 1.4468x; 1.4468x over previous
//
#include <hip/hip_runtime.h>

#define NN 50000
#define NE 800000
#define DD 128
#define NSTRIP 3125   // NN/16
#define NB 196        // dst>>8 buckets (49999>>8 == 195)
#define CHUNK 4096    // edges per shuf/hist block; grid = ceil(NE/CHUNK) = 196
#define MAXB 6144     // bucket capacity (mean 4082, sigma ~64 -> +32 sigma)

// workspace layout, element (4-byte word) offsets
#define OF_BCNT  0            // int[256] bucket counts
#define OF_BBASE 256          // int[257] bucket bases
#define OF_BCUR  768          // int[256] bucket cursors
#define OF_DINV  1024         // float[NN]
#define OF_OFFS  51200        // int[NN+1]
#define OF_TMP   101632       // uint[NE] packed (src<<8 | dstlow)  (3.2 MB)
#define OF_CSRU  901632       // ushort[NE] sorted src  (1.6 MB)
#define OF_G     1301632      // ushort[NN*DD] bf16 g = dinv*h, ROW-MAJOR 256B rows
#define OF_X2    4501632      // float[NN*DD] layer-2 input
#define OF_W1H   10901632     // ushort[16384] fragment order
#define OF_W1L   10909824
#define OF_W2H   10918016
#define OF_W2L   10926208     // end 10934400 words = 43.7 MB

typedef __attribute__((ext_vector_type(8))) short bf8_t;   // 8 bf16 = 4 VGPRs
typedef __attribute__((ext_vector_type(8))) unsigned short us8;
typedef __attribute__((ext_vector_type(4))) float f32x4;

static __device__ __forceinline__ unsigned short f2bf(float f) {
    unsigned int u = __float_as_uint(f);
    unsigned int r = (u + 0x7fffu + ((u >> 16) & 1u)) >> 16;   // RNE
    return (unsigned short)r;
}
static __device__ __forceinline__ float bf2f(unsigned short h) {
    return __uint_as_float(((unsigned int)h) << 16);
}

// both W conversions in one launch; block 0 also zeroes the bucket counters.
// frag g=(ntile*4+kk)*64+lane holds B[k=kk*32+(lane>>4)*8+j][n=ntile*16+(lane&15)]
__global__ void k_wconv(const float* __restrict__ W1, const float* __restrict__ W2,
                        ushort* __restrict__ w1h, ushort* __restrict__ w1l,
                        ushort* __restrict__ w2h, ushort* __restrict__ w2l,
                        int* __restrict__ bcnt) {
    if (blockIdx.x == 0) bcnt[threadIdx.x] = 0;
    int gg = blockIdx.x * 256 + threadIdx.x;
    const float* W = (gg < 2048) ? W1 : W2;
    ushort* wh = (gg < 2048) ? w1h : w2h;
    ushort* wl = (gg < 2048) ? w1l : w2l;
    int g = gg & 2047;
    int ntile = g >> 8;
    int kk = (g >> 6) & 3;
    int lane = g & 63;
    int k0 = kk * 32 + ((lane >> 4) * 8);
    int col = ntile * 16 + (lane & 15);
#pragma unroll
    for (int j = 0; j < 8; ++j) {
        float w = W[(k0 + j) * DD + col];
        unsigned short h = f2bf(w);
        wh[(size_t)g * 8 + j] = h;
        wl[(size_t)g * 8 + j] = f2bf(w - bf2f(h));
    }
}

// 256-bucket histogram of dst>>8, LDS-aggregated
__global__ void k_hist(const int* __restrict__ dst, int* __restrict__ bcnt) {
    __shared__ int lc[256];
    int tid = threadIdx.x;
    lc[tid] = 0;
    __syncthreads();
    int e0 = blockIdx.x * CHUNK;
    int e1 = e0 + CHUNK; if (e1 > NE) e1 = NE;
    for (int e = e0 + tid; e < e1; e += 256)
        atomicAdd(&lc[dst[e] >> 8], 1);
    __syncthreads();
    if (lc[tid]) atomicAdd(&bcnt[tid], lc[tid]);
}

// single-block scan of bucket counts -> bases + cursors; offs[NN] = NE
__global__ void k_bscan(const int* __restrict__ bcnt, int* __restrict__ bbase,
                        int* __restrict__ bcur, int* __restrict__ offs) {
    __shared__ int sh[256];
    int tid = threadIdx.x;
    int v = bcnt[tid];
    sh[tid] = v;
    __syncthreads();
    for (int o = 1; o < 256; o <<= 1) {
        int t = (tid >= o) ? sh[tid - o] : 0;
        __syncthreads();
        sh[tid] += t;
        __syncthreads();
    }
    bbase[tid] = sh[tid] - v;
    bcur[tid]  = sh[tid] - v;
    if (tid == 255) bbase[256] = sh[255];
    if (tid == 0) offs[NN] = NE;
}

// shuffle edges into coarse buckets.  Per block: LDS histogram of its chunk,
// ONE global atomic per touched bucket to reserve a contiguous run, then
// write packed entries -> per-block addresses form ~contiguous runs per
// bucket (lines mostly written by a single block -> no cross-XCD bouncing).
__global__ void k_shuf(const int* __restrict__ src, const int* __restrict__ dst,
                       int* __restrict__ bcur, unsigned int* __restrict__ tmp) {
    __shared__ int lcnt[256];
    __shared__ int lbase[256];
    __shared__ int lcur[256];
    int tid = threadIdx.x;
    lcnt[tid] = 0;
    __syncthreads();
    int e0 = blockIdx.x * CHUNK;
    int e1 = e0 + CHUNK; if (e1 > NE) e1 = NE;
    for (int e = e0 + tid; e < e1; e += 256)
        atomicAdd(&lcnt[dst[e] >> 8], 1);
    __syncthreads();
    if (lcnt[tid]) lbase[tid] = atomicAdd(&bcur[tid], lcnt[tid]);
    lcur[tid] = 0;
    __syncthreads();
    for (int e = e0 + tid; e < e1; e += 256) {
        int d = dst[e], s = src[e];
        int b = d >> 8;
        int r = atomicAdd(&lcur[b], 1);
        tmp[lbase[b] + r] = ((unsigned int)s << 8) | (unsigned int)(d & 255);
    }
}

// per-bucket LDS counting sort -> final CSR slab, offs[], dinv[].
__global__ __launch_bounds__(256) void k_sort(const int* __restrict__ bbase,
                                              const unsigned int* __restrict__ tmp,
                                              ushort* __restrict__ csru,
                                              int* __restrict__ offs,
                                              float* __restrict__ dinv) {
    __shared__ unsigned int ent[MAXB];
    __shared__ int cnt[256];
    __shared__ int boff[256];
    __shared__ int cur[256];
    int b = blockIdx.x, tid = threadIdx.x;
    int base = bbase[b];
    int nb = bbase[b + 1] - base;
    cnt[tid] = 0;
    __syncthreads();
    for (int i = tid; i < nb; i += 256) {
        unsigned int v = tmp[base + i];
        ent[i] = v;
        atomicAdd(&cnt[v & 255], 1);
    }
    __syncthreads();
    int v = cnt[tid];
    boff[tid] = v;
    __syncthreads();
    for (int o = 1; o < 256; o <<= 1) {
        int t = (tid >= o) ? boff[tid - o] : 0;
        __syncthreads();
        boff[tid] += t;
        __syncthreads();
    }
    int excl = boff[tid] - v;
    int node = b * 256 + tid;
    if (node < NN) {
        offs[node] = base + excl;
        dinv[node] = rsqrtf((float)(v + 1));   // +1 self-loop
    }
    cur[tid] = excl;
    __syncthreads();
    for (int i = tid; i < nb; i += 256) {
        unsigned int e = ent[i];
        int bin = e & 255;
        int r = atomicAdd(&cur[bin], 1);
        csru[base + r] = (ushort)(e >> 8);
    }
}

// MFMA GEMM, split-bf16 (hi*hi + hi*lo + lo*hi ~ fp32 accuracy).
// Reads fp32 X directly, Dekker-splits in-register.
// Epilogue scales rows by dinv, stores bf16 g row-major (256B rows).
__global__ __launch_bounds__(256) void k_mgemm(const float* __restrict__ X,
                                               const ushort* __restrict__ wh,
                                               const ushort* __restrict__ wl,
                                               const float* __restrict__ dinv,
                                               ushort* __restrict__ G) {
    int wave = threadIdx.x >> 6;
    int lane = threadIdx.x & 63;
    int strip = blockIdx.x * 4 + wave;
    if (strip >= NSTRIP) return;
    int rb = strip << 4;
    int m = lane & 15;
    int quad = lane >> 4;
    const float* ar = X + (size_t)(rb + m) * DD;
    f32x4 acc[8];
#pragma unroll
    for (int t = 0; t < 8; ++t) acc[t] = (f32x4){0.f, 0.f, 0.f, 0.f};
#pragma unroll
    for (int kk = 0; kk < 4; ++kk) {
        float4 xa = *(const float4*)(ar + kk * 32 + quad * 8);
        float4 xb = *(const float4*)(ar + kk * 32 + quad * 8 + 4);
        float xs[8] = {xa.x, xa.y, xa.z, xa.w, xb.x, xb.y, xb.z, xb.w};
        bf8_t ah, al;
#pragma unroll
        for (int j = 0; j < 8; ++j) {
            unsigned short hh = f2bf(xs[j]);
            ah[j] = (short)hh;
            al[j] = (short)f2bf(xs[j] - bf2f(hh));
        }
#pragma unroll
        for (int t = 0; t < 8; ++t) {
            size_t bo = ((size_t)(t * 4 + kk) * 64 + lane) * 8;
            bf8_t bh = *(const bf8_t*)(wh + bo);
            bf8_t bl = *(const bf8_t*)(wl + bo);
            acc[t] = __builtin_amdgcn_mfma_f32_16x16x32_bf16(ah, bh, acc[t], 0, 0, 0);
            acc[t] = __builtin_amdgcn_mfma_f32_16x16x32_bf16(ah, bl, acc[t], 0, 0, 0);
            acc[t] = __builtin_amdgcn_mfma_f32_16x16x32_bf16(al, bh, acc[t], 0, 0, 0);
        }
    }
    // C/D layout (m89-verified): col = lane&15, row = quad*4 + reg
    float dv[4];
#pragma unroll
    for (int r = 0; r < 4; ++r) dv[r] = dinv[rb + quad * 4 + r];
#pragma unroll
    for (int t = 0; t < 8; ++t) {
#pragma unroll
        for (int r = 0; r < 4; ++r)
            G[(size_t)(rb + quad * 4 + r) * DD + t * 16 + m] = f2bf(dv[r] * acc[t][r]);
    }
}

// out[i] = relu( dinv[i] * ( sum_{e: dst==i} g[src_e] + g[i] ) + bias )
// One wave per node.  4 quarter-waves of 16 lanes x ushort8 (16B/lane = one
// full 256B row per quarter per iteration); quarters take interleaved edge
// slots; 2x unroll -> 8 independent row gathers in flight per wave.
// Cross-quarter reduce via shfl_xor(16) + shfl_xor(32).
__global__ void k_agg(const ushort* __restrict__ g, const float* __restrict__ dinv,
                      const int* __restrict__ offs, const ushort* __restrict__ csru,
                      const float* __restrict__ bias, float* __restrict__ outf) {
    int wave = threadIdx.x >> 6;
    int lane = threadIdx.x & 63;
    int node = blockIdx.x * 4 + wave;   // grid = NN/4 exactly
    int q = lane >> 4;
    int l = lane & 15;
    float a0[8] = {0.f, 0.f, 0.f, 0.f, 0.f, 0.f, 0.f, 0.f};
    float a1[8] = {0.f, 0.f, 0.f, 0.f, 0.f, 0.f, 0.f, 0.f};
    int e  = offs[node] + q;
    int e1 = offs[node + 1];
    for (; e + 4 < e1; e += 8) {
        int s0 = csru[e];
        int s1 = csru[e + 4];
        us8 v0 = *(const us8*)(g + (size_t)s0 * DD + 8 * l);
        us8 v1 = *(const us8*)(g + (size_t)s1 * DD + 8 * l);
#pragma unroll
        for (int j = 0; j < 8; ++j) {
            a0[j] += bf2f(v0[j]);
            a1[j] += bf2f(v1[j]);
        }
    }
    if (e < e1) {
        int s0 = csru[e];
        us8 v0 = *(const us8*)(g + (size_t)s0 * DD + 8 * l);
#pragma unroll
        for (int j = 0; j < 8; ++j) a0[j] += bf2f(v0[j]);
    }
    if (q == 0) {  // self-loop term: dinv^2*h = dinv*g, counted once
        us8 v = *(const us8*)(g + (size_t)node * DD + 8 * l);
#pragma unroll
        for (int j = 0; j < 8; ++j) a0[j] += bf2f(v[j]);
    }
#pragma unroll
    for (int j = 0; j < 8; ++j) {
        a0[j] += a1[j];
        a0[j] += __shfl_xor(a0[j], 16, 64);
        a0[j] += __shfl_xor(a0[j], 32, 64);
    }
    if (q == 0) {
        float di = dinv[node];
        float* op = outf + (size_t)node * DD + 8 * l;
        const float* bp = bias + 8 * l;
        float4 o0, o1;
        o0.x = fmaxf(di * a0[0] + bp[0], 0.f);
        o0.y = fmaxf(di * a0[1] + bp[1], 0.f);
        o0.z = fmaxf(di * a0[2] + bp[2], 0.f);
        o0.w = fmaxf(di * a0[3] + bp[3], 0.f);
        o1.x = fmaxf(di * a0[4] + bp[4], 0.f);
        o1.y = fmaxf(di * a0[5] + bp[5], 0.f);
        o1.z = fmaxf(di * a0[6] + bp[6], 0.f);
        o1.w = fmaxf(di * a0[7] + bp[7], 0.f);
        *(float4*)op = o0;
        *(float4*)(op + 4) = o1;
    }
}

extern "C" void kernel_launch(void* const* d_in, const int* in_sizes, int n_in,
                              void* d_out, int out_size, void* d_ws, size_t ws_size,
                              hipStream_t stream) {
    const float* x  = (const float*)d_in[0];
    const int*   ei = (const int*)d_in[1];
    const float* W1 = (const float*)d_in[2];
    const float* b1 = (const float*)d_in[3];
    const float* W2 = (const float*)d_in[4];
    const float* b2 = (const float*)d_in[5];
    float* out = (float*)d_out;

    const int* src = ei;        // edge_index[0]
    const int* dst = ei + NE;   // edge_index[1]

    int*          wsi  = (int*)d_ws;
    float*        wsf  = (float*)d_ws;
    ushort*       wsu  = (ushort*)d_ws;
    unsigned int* wsuw = (unsigned int*)d_ws;
    int*    bcnt  = wsi + OF_BCNT;
    int*    bbase = wsi + OF_BBASE;
    int*    bcur  = wsi + OF_BCUR;
    float*  dinv  = wsf + OF_DINV;
    int*    offs  = wsi + OF_OFFS;
    unsigned int* tmp = wsuw + OF_TMP;
    ushort* csru  = wsu + (size_t)OF_CSRU * 2;
    ushort* gbuf  = wsu + (size_t)OF_G * 2;
    float*  x2    = wsf + OF_X2;
    ushort* w1h   = wsu + (size_t)OF_W1H * 2;
    ushort* w1l   = wsu + (size_t)OF_W1L * 2;
    ushort* w2h   = wsu + (size_t)OF_W2H * 2;
    ushort* w2l   = wsu + (size_t)OF_W2L * 2;

    const int chunks = (NE + CHUNK - 1) / CHUNK;  // 196

    // W conversions + bcnt zeroing (one launch), then bucket-sort CSR build
    hipLaunchKernelGGL(k_wconv, dim3(16), dim3(256), 0, stream,
                       W1, W2, w1h, w1l, w2h, w2l, bcnt);
    hipLaunchKernelGGL(k_hist,  dim3(chunks), dim3(256), 0, stream, dst, bcnt);
    hipLaunchKernelGGL(k_bscan, dim3(1), dim3(256), 0, stream, bcnt, bbase, bcur, offs);
    hipLaunchKernelGGL(k_shuf,  dim3(chunks), dim3(256), 0, stream, src, dst, bcur, tmp);
    hipLaunchKernelGGL(k_sort,  dim3(NB), dim3(256), 0, stream, bbase, tmp, csru, offs, dinv);

    const int gblocks = (NSTRIP + 3) / 4;  // 782

    // layer 1: g = dinv*(x @ W1) (MFMA, bf16) ; agg -> relu(dinv*sum + b1) fp32
    hipLaunchKernelGGL(k_mgemm, dim3(gblocks), dim3(256), 0, stream, x, w1h, w1l, dinv, gbuf);
    hipLaunchKernelGGL(k_agg,   dim3(NN / 4), dim3(256), 0, stream,
                       gbuf, dinv, offs, csru, b1, x2);
    // layer 2
    hipLaunchKernelGGL(k_mgemm, dim3(gblocks), dim3(256), 0, stream, x2, w2h, w2l, dinv, gbuf);
    hipLaunchKernelGGL(k_agg,   dim3(NN / 4), dim3(256), 0, stream,
                       gbuf, dinv, offs, csru, b2, out);
}